// Round 5
// baseline (1293.057 us; speedup 1.0000x reference)
//
#include <hip/hip_runtime.h>
#include <math.h>

#define N_NODES 2048
#define HID 64
#define BATCH 8
#define SEQ 32
#define CAP 128          // ELL slots per row (nnz/row ~33, padded to x8)
#define TB 256           // SEQ*BATCH
#define NH (N_NODES*HID) // 131072 per batch

typedef __attribute__((ext_vector_type(8))) _Float16 half8;

__device__ __forceinline__ float fast_sig(float s) {
  return 1.f / (1.f + __expf(-s));
}
__device__ __forceinline__ float fast_tanh(float s) {
  float e = __expf(-2.f * fabsf(s));
  float t = 1.f - 2.f * e / (1.f + e);
  return copysignf(t, s);
}

// ---------------- Kernel 0: build padded ELL (colh = col*HID) ---------------
__global__ __launch_bounds__(256) void k_build_ell(
    const float* __restrict__ L, float* __restrict__ ell_val,
    int* __restrict__ ell_colh, int* __restrict__ ell_cnt) {
  int wave = (blockIdx.x * blockDim.x + threadIdx.x) >> 6;
  int lane = threadIdx.x & 63;
  if (wave >= N_NODES) return;
  const float* row = L + (size_t)wave * N_NODES;
  int base = 0;
  for (int c = 0; c < N_NODES / 64; ++c) {
    int col = c * 64 + lane;
    float v = row[col];
    bool nz = (v != 0.0f);
    unsigned long long mask = __ballot(nz);
    int before = __popcll(mask & ((1ull << lane) - 1ull));
    if (nz) {
      int slot = base + before;
      if (slot < CAP) {
        ell_colh[wave * CAP + slot] = col * HID;
        ell_val[wave * CAP + slot] = v;
      }
    }
    base += __popcll(mask);
  }
  if (base > CAP) base = CAP;
  int pad = (base + 7) & ~7;
  if (pad > CAP) pad = CAP;
  for (int s = base + lane; s < pad; s += 64) {
    ell_colh[wave * CAP + s] = 0;
    ell_val[wave * CAP + s] = 0.f;
  }
  if (lane == 0) ell_cnt[wave] = pad;
}

// ---------------- Transpose x[b][t][n] -> xT[n][tb],  tb = t*8 + b ----------
__global__ __launch_bounds__(256) void k_xt(const float* __restrict__ x,
                                            float* __restrict__ xT) {
  __shared__ float s[32][65];
  int n0  = (blockIdx.x & 63) * 32;
  int tb0 = (blockIdx.x >> 6) * 64;
  for (int idx = threadIdx.x; idx < 32 * 64; idx += 256) {
    int ln = idx & 31, ltb = idx >> 5;
    int tb = tb0 + ltb; int b = tb & 7, t = tb >> 3;
    s[ln][ltb] = x[((size_t)b * SEQ + t) * N_NODES + n0 + ln];
  }
  __syncthreads();
  for (int idx = threadIdx.x; idx < 32 * 64; idx += 256) {
    int ln = idx >> 6, ltb = idx & 63;
    xT[(size_t)(n0 + ln) * TB + tb0 + ltb] = s[ln][ltb];
  }
}

// ---------------- LxT[m][tb] = sum_n L[m,n] * xT[n][tb] ---------------------
__global__ __launch_bounds__(512) void k_spmm_x(
    const float* __restrict__ xT, const float* __restrict__ ell_val,
    const int* __restrict__ ell_colh, const int* __restrict__ ell_cnt,
    float* __restrict__ LxT) {
  int m = (blockIdx.x * blockDim.x + threadIdx.x) >> 6;
  int lane = threadIdx.x & 63;
  if (m >= N_NODES) return;
  const int* cp = ell_colh + m * CAP;
  const float* vp = ell_val + m * CAP;
  int cnt = ell_cnt[m];
  float4 acc = {0.f, 0.f, 0.f, 0.f};
  for (int k = 0; k < cnt; k += 4) {
    int4 c = *(const int4*)(cp + k);
    float4 v = *(const float4*)(vp + k);
    float4 xa = *(const float4*)&xT[(size_t)c.x * 4 + lane * 4];
    float4 xb = *(const float4*)&xT[(size_t)c.y * 4 + lane * 4];
    float4 xc = *(const float4*)&xT[(size_t)c.z * 4 + lane * 4];
    float4 xd = *(const float4*)&xT[(size_t)c.w * 4 + lane * 4];
    acc.x = fmaf(v.x, xa.x, acc.x); acc.y = fmaf(v.x, xa.y, acc.y);
    acc.z = fmaf(v.x, xa.z, acc.z); acc.w = fmaf(v.x, xa.w, acc.w);
    acc.x = fmaf(v.y, xb.x, acc.x); acc.y = fmaf(v.y, xb.y, acc.y);
    acc.z = fmaf(v.y, xb.z, acc.z); acc.w = fmaf(v.y, xb.w, acc.w);
    acc.x = fmaf(v.z, xc.x, acc.x); acc.y = fmaf(v.z, xc.y, acc.y);
    acc.z = fmaf(v.z, xc.z, acc.z); acc.w = fmaf(v.z, xc.w, acc.w);
    acc.x = fmaf(v.w, xd.x, acc.x); acc.y = fmaf(v.w, xd.y, acc.y);
    acc.z = fmaf(v.w, xd.z, acc.z); acc.w = fmaf(v.w, xd.w, acc.w);
  }
  *(float4*)&LxT[(size_t)m * TB + lane * 4] = acc;
}

// ---------------- Kernel 1: gates from fp16-packed state --------------------
// statepk[n*64+h] is half8 over b. Lane l gathers (h=l, all 8 b) per nnz:
// ONE dwordx4 per nnz covers the full 8x64 row block at half fp32 bytes.
__global__ __launch_bounds__(256, 4) void k_gates(
    const half8* __restrict__ statepk, const float* __restrict__ LxT,
    const float* __restrict__ ell_val, const int* __restrict__ ell_colh,
    const int* __restrict__ ell_cnt, const float* __restrict__ Wg,
    const float* __restrict__ bg, half8* __restrict__ rspk,
    half8* __restrict__ upk, int t) {
  __shared__ float4 sWv4[128][16];
  __shared__ float sWx[128];
  __shared__ float sb[128];
  __shared__ float sdiff[4][8][64];   // [wv][b][h]
  for (int idx = threadIdx.x; idx < 128 * 16; idx += 256) {
    int o = idx >> 4, p = idx & 15;
    int j = p ^ (o & 15);
    const float* src = Wg + o * 65 + 1 + j * 4;
    sWv4[o][p] = make_float4(src[0], src[1], src[2], src[3]);
  }
  if (threadIdx.x < 128) {
    sWx[threadIdx.x] = Wg[threadIdx.x * 65];
    sb[threadIdx.x]  = bg[threadIdx.x];
  }
  __syncthreads();
  int wv = threadIdx.x >> 6, lane = threadIdx.x & 63;
  int m = blockIdx.x * 4 + wv;
  const half8* pk = statepk + lane;       // pk[colh] = statepk[col*64 + lane]
  const int* cp = ell_colh + m * CAP;
  const float* vp = ell_val + m * CAP;
  int cnt = ell_cnt[m];
  float acc0=0.f,acc1=0.f,acc2=0.f,acc3=0.f,acc4=0.f,acc5=0.f,acc6=0.f,acc7=0.f;
  for (int k = 0; k < cnt; k += 8) {
    int4 ca = *(const int4*)(cp + k);
    int4 cb = *(const int4*)(cp + k + 4);
    float4 va = *(const float4*)(vp + k);
    float4 vb = *(const float4*)(vp + k + 4);
#define GATH(C, V) { half8 hv = pk[C]; \
    acc0 = fmaf(V, (float)hv[0], acc0); acc1 = fmaf(V, (float)hv[1], acc1); \
    acc2 = fmaf(V, (float)hv[2], acc2); acc3 = fmaf(V, (float)hv[3], acc3); \
    acc4 = fmaf(V, (float)hv[4], acc4); acc5 = fmaf(V, (float)hv[5], acc5); \
    acc6 = fmaf(V, (float)hv[6], acc6); acc7 = fmaf(V, (float)hv[7], acc7); }
    GATH(ca.x, va.x) GATH(ca.y, va.y) GATH(ca.z, va.z) GATH(ca.w, va.w)
    GATH(cb.x, vb.x) GATH(cb.y, vb.y) GATH(cb.z, vb.z) GATH(cb.w, vb.w)
#undef GATH
  }
  sdiff[wv][0][lane] = acc0; sdiff[wv][1][lane] = acc1;
  sdiff[wv][2][lane] = acc2; sdiff[wv][3][lane] = acc3;
  sdiff[wv][4][lane] = acc4; sdiff[wv][5][lane] = acc5;
  sdiff[wv][6][lane] = acc6; sdiff[wv][7][lane] = acc7;
  float4 LxLo = *(const float4*)&LxT[(size_t)m * TB + t * BATCH];
  float4 LxHi = *(const float4*)&LxT[(size_t)m * TB + t * BATCH + 4];
  float Lx8[8] = {LxLo.x, LxLo.y, LxLo.z, LxLo.w, LxHi.x, LxHi.y, LxHi.z, LxHi.w};
  int o0 = lane, o1 = lane + 64;
  int sw0 = o0 & 15, sw1 = o1 & 15;
  float wx0 = sWx[o0], bb0 = sb[o0];
  float wx1 = sWx[o1], bb1 = sb[o1];
  float s0[8], s1[8];
  #pragma unroll
  for (int b = 0; b < 8; ++b) {
    s0[b] = fmaf(Lx8[b], wx0, bb0);
    s1[b] = fmaf(Lx8[b], wx1, bb1);
  }
  #pragma unroll
  for (int j = 0; j < 16; ++j) {
    float4 w0 = sWv4[o0][j ^ sw0];
    float4 w1 = sWv4[o1][j ^ sw1];
    #pragma unroll
    for (int b = 0; b < 8; ++b) {
      const float4 d = *(const float4*)&sdiff[wv][b][j * 4];  // broadcast
      s0[b] += d.x * w0.x + d.y * w0.y + d.z * w0.z + d.w * w0.w;
      s1[b] += d.x * w1.x + d.y * w1.y + d.z * w1.z + d.w * w1.w;
    }
  }
  if (m < N_NODES / 2) {
    // r-half: flat gate idx == flat state idx. rep0 -> node 2m, rep1 -> 2m+1.
    half8 spk0 = pk[m * 128];          // statepk[(2m)*64 + lane]
    half8 spk1 = pk[m * 128 + 64];     // statepk[(2m+1)*64 + lane]
    half8 r0, r1;
    #pragma unroll
    for (int b = 0; b < 8; ++b) {
      r0[b] = (_Float16)(fast_sig(s0[b]) * (float)spk0[b]);
      r1[b] = (_Float16)(fast_sig(s1[b]) * (float)spk1[b]);
    }
    half8* rp = rspk + lane;
    rp[m * 128] = r0;
    rp[m * 128 + 64] = r1;
  } else {
    int mm = m - N_NODES / 2;
    half8 u0, u1;
    #pragma unroll
    for (int b = 0; b < 8; ++b) {
      u0[b] = (_Float16)fast_sig(s0[b]);
      u1[b] = (_Float16)fast_sig(s1[b]);
    }
    half8* up = upk + lane;
    up[mm * 128] = u0;
    up[mm * 128 + 64] = u1;
  }
}

// ---------------- Kernel 2: cand + GRU update (gathers rspk) ----------------
__global__ __launch_bounds__(256, 4) void k_cand(
    const half8* __restrict__ statepk, const float* __restrict__ LxT,
    const float* __restrict__ ell_val, const int* __restrict__ ell_colh,
    const int* __restrict__ ell_cnt, const float* __restrict__ Wc,
    const float* __restrict__ bc, const half8* __restrict__ rspk,
    const half8* __restrict__ upk, half8* __restrict__ statepk_next,
    float* __restrict__ out, int t) {
  __shared__ float4 sWv4[64][16];
  __shared__ float sWx[64];
  __shared__ float sb[64];
  __shared__ float sdiff[4][8][64];
  for (int idx = threadIdx.x; idx < 64 * 16; idx += 256) {
    int o = idx >> 4, p = idx & 15;
    int j = p ^ (o & 15);
    const float* src = Wc + o * 65 + 1 + j * 4;
    sWv4[o][p] = make_float4(src[0], src[1], src[2], src[3]);
  }
  if (threadIdx.x < 64) {
    sWx[threadIdx.x] = Wc[threadIdx.x * 65];
    sb[threadIdx.x]  = bc[threadIdx.x];
  }
  __syncthreads();
  int wv = threadIdx.x >> 6, lane = threadIdx.x & 63;
  int m = blockIdx.x * 4 + wv;
  const half8* pk = rspk + lane;
  const int* cp = ell_colh + m * CAP;
  const float* vp = ell_val + m * CAP;
  int cnt = ell_cnt[m];
  float acc0=0.f,acc1=0.f,acc2=0.f,acc3=0.f,acc4=0.f,acc5=0.f,acc6=0.f,acc7=0.f;
  for (int k = 0; k < cnt; k += 8) {
    int4 ca = *(const int4*)(cp + k);
    int4 cb = *(const int4*)(cp + k + 4);
    float4 va = *(const float4*)(vp + k);
    float4 vb = *(const float4*)(vp + k + 4);
#define GATH(C, V) { half8 hv = pk[C]; \
    acc0 = fmaf(V, (float)hv[0], acc0); acc1 = fmaf(V, (float)hv[1], acc1); \
    acc2 = fmaf(V, (float)hv[2], acc2); acc3 = fmaf(V, (float)hv[3], acc3); \
    acc4 = fmaf(V, (float)hv[4], acc4); acc5 = fmaf(V, (float)hv[5], acc5); \
    acc6 = fmaf(V, (float)hv[6], acc6); acc7 = fmaf(V, (float)hv[7], acc7); }
    GATH(ca.x, va.x) GATH(ca.y, va.y) GATH(ca.z, va.z) GATH(ca.w, va.w)
    GATH(cb.x, vb.x) GATH(cb.y, vb.y) GATH(cb.z, vb.z) GATH(cb.w, vb.w)
#undef GATH
  }
  sdiff[wv][0][lane] = acc0; sdiff[wv][1][lane] = acc1;
  sdiff[wv][2][lane] = acc2; sdiff[wv][3][lane] = acc3;
  sdiff[wv][4][lane] = acc4; sdiff[wv][5][lane] = acc5;
  sdiff[wv][6][lane] = acc6; sdiff[wv][7][lane] = acc7;
  float4 LxLo = *(const float4*)&LxT[(size_t)m * TB + t * BATCH];
  float4 LxHi = *(const float4*)&LxT[(size_t)m * TB + t * BATCH + 4];
  float Lx8[8] = {LxLo.x, LxLo.y, LxLo.z, LxLo.w, LxHi.x, LxHi.y, LxHi.z, LxHi.w};
  int o = lane, sw = o & 15;
  float wx = sWx[o], bias = sb[o];
  float s[8];
  #pragma unroll
  for (int b = 0; b < 8; ++b) s[b] = fmaf(Lx8[b], wx, bias);
  #pragma unroll
  for (int j = 0; j < 16; ++j) {
    float4 w = sWv4[o][j ^ sw];
    #pragma unroll
    for (int b = 0; b < 8; ++b) {
      const float4 d = *(const float4*)&sdiff[wv][b][j * 4];
      s[b] += d.x * w.x + d.y * w.y + d.z * w.z + d.w * w.w;
    }
  }
  half8 hp = (statepk + lane)[m * 64];   // statepk[m*64+lane]
  half8 up = (upk + lane)[m * 64];
  half8 npk;
  float* op = out + (size_t)t * BATCH * NH + m * HID + lane;
  #pragma unroll
  for (int b = 0; b < 8; ++b) {
    float u = (float)up[b];
    float nh = u * (float)hp[b] + (1.f - u) * fast_tanh(s[b]);
    npk[b] = (_Float16)nh;
    op[(size_t)b * NH] = nh;
  }
  (statepk_next + lane)[m * 64] = npk;
}

extern "C" void kernel_launch(void* const* d_in, const int* in_sizes, int n_in,
                              void* d_out, int out_size, void* d_ws, size_t ws_size,
                              hipStream_t stream) {
  const float* x  = (const float*)d_in[0];
  const float* L  = (const float*)d_in[1];
  const float* Wg = (const float*)d_in[2];
  const float* bg = (const float*)d_in[3];
  const float* Wc = (const float*)d_in[4];
  const float* bc = (const float*)d_in[5];
  float* out = (float*)d_out;
  float* ws = (float*)d_ws;

  float* ell_val  = ws;                                     // N*CAP f
  int*   ell_colh = (int*)(ws + (size_t)N_NODES * CAP);     // N*CAP i
  int*   ell_cnt  = (int*)(ws + (size_t)2 * N_NODES * CAP); // N i
  float* xT    = ws + (size_t)2 * N_NODES * CAP + N_NODES;  // N*TB f
  float* LxT   = xT + (size_t)N_NODES * TB;                 // N*TB f
  float* fend  = LxT + (size_t)N_NODES * TB;
  half8* stA  = (half8*)fend;                               // N*64 half8 = 2MB
  half8* stB  = stA + (size_t)N_NODES * HID;
  half8* rspk = stB + (size_t)N_NODES * HID;
  half8* upk  = rspk + (size_t)N_NODES * HID;

  k_build_ell<<<N_NODES / 4, 256, 0, stream>>>(L, ell_val, ell_colh, ell_cnt);
  k_xt<<<256, 256, 0, stream>>>(x, xT);
  k_spmm_x<<<N_NODES / 8, 512, 0, stream>>>(xT, ell_val, ell_colh, ell_cnt, LxT);
  hipMemsetAsync(stA, 0, (size_t)N_NODES * HID * sizeof(half8), stream);

  half8* cur = stA;
  half8* nxt = stB;
  for (int t = 0; t < SEQ; ++t) {
    k_gates<<<N_NODES / 4, 256, 0, stream>>>(cur, LxT, ell_val, ell_colh,
                                             ell_cnt, Wg, bg, rspk, upk, t);
    k_cand<<<N_NODES / 4, 256, 0, stream>>>(cur, LxT, ell_val, ell_colh,
                                            ell_cnt, Wc, bc, rspk, upk, nxt,
                                            out, t);
    half8* tmp = cur; cur = nxt; nxt = tmp;
  }
}